// Round 7
// baseline (308.334 us; speedup 1.0000x reference)
//
#include <hip/hip_runtime.h>

// Problem constants (B=16, C1=C2=128, H=W=80, K=3, pad=1, stride=1)
#define HH 80
#define WW 80
#define C1 128
#define C2 128
#define NB 16
#define HWSZ 6400      // 80*80
#define KKT 1152       // C1*9 (GEMM K, reordered as k' = p*128 + c)

typedef __attribute__((ext_vector_type(8))) short bf16x8;
typedef __attribute__((ext_vector_type(4))) float f32x4;

union PkU  { uint4 v; uint d[4]; bf16x8 h; };
union CornU { uint4 v; uint d[4]; };

__device__ inline ushort f2bf(float f) {
  unsigned u = __float_as_uint(f);
  return (ushort)((u + 0x7FFFu + ((u >> 16) & 1u)) >> 16);
}

// packed f32x2 -> bf16x2 (RNE, identical rounding to f2bf)
__device__ inline uint cvtpk(float lo, float hi) {
  uint r;
  asm("v_cvt_pk_bf16_f32 %0, %1, %2" : "=v"(r) : "v"(lo), "v"(hi));
  return r;
}
__device__ inline float bfu_lo(uint w) { return __uint_as_float(w << 16); }
__device__ inline float bfu_hi(uint w) { return __uint_as_float(w & 0xFFFF0000u); }

// async global->LDS, 16B per lane, LDS dest = wave-uniform base (+lane*16 by HW)
// NOTE: completion tracked by vmcnt; CALLER must s_waitcnt before ds_read.
__device__ inline void gload_lds16(const ushort* g, ushort* l) {
  __builtin_amdgcn_global_load_lds(
      (const __attribute__((address_space(1))) void*)g,
      (__attribute__((address_space(3))) void*)l, 16, 0, 0);
}

// ---------------------------------------------------------------------------
// Kernel A+B merged: transpose x -> xt (blocks 0..3199) and weight prep
// (blocks 3200..3919).
// ---------------------------------------------------------------------------
__global__ __launch_bounds__(256) void xpose_prep_kernel(
    const float* __restrict__ x, ushort* __restrict__ xt,
    const float* __restrict__ w, const float* __restrict__ ow,
    ushort* __restrict__ wbf, ushort* __restrict__ wobf) {
  __shared__ float ts[64][65];
  const int idx = blockIdx.x;
  const int tid = threadIdx.x;

  if (idx < 3200) {
    const int b = idx / 200;
    const int rem = idx % 200;
    const int c0 = (rem / 100) * 64;
    const int hw0 = (rem % 100) * 64;
    const int lane = tid & 63;

    #pragma unroll
    for (int it = 0; it < 16; it++) {
      int cl = (tid >> 6) + it * 4;
      ts[cl][lane] = x[((size_t)(b * C1 + c0 + cl)) * HWSZ + hw0 + lane];
    }
    __syncthreads();

    #pragma unroll
    for (int it = 0; it < 2; it++) {
      int u = tid + it * 256;
      int j = u >> 3, cg = u & 7;
      CornU pk;
      #pragma unroll
      for (int m = 0; m < 4; m++)
        pk.d[m] = cvtpk(ts[cg * 8 + 2 * m][j], ts[cg * 8 + 2 * m + 1][j]);
      *(uint4*)(xt + ((size_t)b * HWSZ + hw0 + j) * C1 + c0 + cg * 8) = pk.v;
    }
  } else {
    int o = (idx - 3200) * 256 + tid;            // 0..184319
    if (o < C2 * KKT) {
      int j  = o & 7;
      int ch = (o >> 3) & 127;
      int kt = o >> 12;
      int kg = (o >> 10) & 3;
      int kprime = kt * 32 + kg * 8 + j;
      int p = kprime >> 7;
      int c = kprime & 127;
      wbf[o] = f2bf(w[(size_t)ch * KKT + c * 9 + p]);
    } else {
      int o2 = o - C2 * KKT;
      int j  = o2 & 7;
      int ch = (o2 >> 3) & 31;
      int kt = o2 >> 10;
      int kg = (o2 >> 8) & 3;
      int kprime = kt * 32 + kg * 8 + j;
      int p = kprime >> 7;
      int c = kprime & 127;
      wobf[o2] = (ch < 18) ? f2bf(ow[(size_t)ch * KKT + c * 9 + p]) : (ushort)0;
    }
  }
}

// ---------------------------------------------------------------------------
// Kernel C: offset conv (round-0 verbatim — known-good).
// ---------------------------------------------------------------------------
__global__ __launch_bounds__(256) void offset_mfma_kernel(
    const ushort* __restrict__ xt, const ushort* __restrict__ wobf,
    const float* __restrict__ ob, float* __restrict__ offs) {
  const int bid = blockIdx.x;                    // 0..1599
  const int b = bid & 15;
  const int tile = bid >> 4;                     // 0..99
  const int h0 = (tile / 5) * 4;
  const int w0 = (tile % 5) * 16;
  const int tid = threadIdx.x;
  const int lane = tid & 63;
  const int wave = tid >> 6;
  const int pl = lane & 15, cg = lane >> 4;
  const int spos = wave * 16 + pl;

  __shared__ ushort s_t[4][64][8];               // 4 KB
  __shared__ ushort w_t[4][32][8];               // 2 KB

  f32x4 acc0 = {0.f, 0.f, 0.f, 0.f}, acc1 = {0.f, 0.f, 0.f, 0.f};
  const ushort* xtb = xt + (size_t)b * HWSZ * C1;

  auto shifted_load = [&](int kt) -> uint4 {
    const int p = kt >> 2, c0 = (kt & 3) << 5;
    const int row = h0 + (spos >> 4) + (p / 3) - 1;
    const int col = w0 + (spos & 15) + (p % 3) - 1;
    uint4 v = {0u, 0u, 0u, 0u};
    if ((unsigned)row < (unsigned)HH && (unsigned)col < (unsigned)WW)
      v = *(const uint4*)(xtb + ((size_t)row * WW + col) * C1 + c0 + cg * 8);
    return v;
  };

  uint4 cv = shifted_load(0);
  uint4 cw = {0u, 0u, 0u, 0u};
  if (tid < 128) cw = ((const uint4*)wobf)[tid];

  #pragma unroll 4
  for (int kt = 0; kt < 36; ++kt) {
    uint4 nv = {0u, 0u, 0u, 0u}, nw = {0u, 0u, 0u, 0u};
    if (kt < 35) {
      nv = shifted_load(kt + 1);
      if (tid < 128) nw = ((const uint4*)(wobf + (size_t)(kt + 1) * 1024))[tid];
    }

    __syncthreads();
    ((uint4*)s_t)[cg * 64 + spos] = cv;
    if (tid < 128) ((uint4*)w_t)[tid] = cw;
    __syncthreads();

    const int q = lane >> 4, c15 = lane & 15;
    bf16x8 bfrag = *(const bf16x8*)&s_t[q][wave * 16 + c15][0];
    bf16x8 a0 = *(const bf16x8*)&w_t[q][c15][0];
    bf16x8 a1 = *(const bf16x8*)&w_t[q][16 + c15][0];
    acc0 = __builtin_amdgcn_mfma_f32_16x16x32_bf16(a0, bfrag, acc0, 0, 0, 0);
    acc1 = __builtin_amdgcn_mfma_f32_16x16x32_bf16(a1, bfrag, acc1, 0, 0, 0);

    cv = nv; cw = nw;
  }

  {
    const int q = lane >> 4, c15 = lane & 15;
    const int ho = h0 + wave, wo = w0 + c15;
    #pragma unroll
    for (int r = 0; r < 4; r++) {
      int ch = q * 4 + r;
      if (ch < 18)
        offs[((size_t)b * 18 + ch) * HWSZ + ho * WW + wo] = acc0[r] + ob[ch];
      int ch1 = 16 + q * 4 + r;
      if (ch1 < 18)
        offs[((size_t)b * 18 + ch1) * HWSZ + ho * WW + wo] = acc1[r] + ob[ch1];
    }
  }
}

// ---------------------------------------------------------------------------
// Kernel D: fused bilinear + MFMA, ZERO barriers ("wave-autonomous"),
// with counted vmcnt protecting the private weight buffer:
//   per-iteration vmem queue (oldest->youngest):
//     gathers(i)[4] , stage(i)[8] , gathers(i+1)[4]
//   s_waitcnt vmcnt(4) before the MFMA cluster retires stage(i) while
//   leaving gathers(i+1) in flight -> no drain, 2-chunk gather pipeline
//   preserved, no wave ever coupled to another wave's loads.
// Issue order is pinned by empty memory-clobber asm so the count is exact.
// ---------------------------------------------------------------------------
struct Geo { float f00, f01, f10, f11; int o00, o01, o10, o11; };

__device__ inline Geo make_geo(float4 cd) {
  Geo g;
  int y0 = (int)cd.x, x0 = (int)cd.y;
  float wy1 = cd.z, wx1 = cd.w;
  float fy0 = ((unsigned)y0 < (unsigned)HH) ? (1.f - wy1) : 0.f;
  float fy1 = ((unsigned)(y0 + 1) < (unsigned)HH) ? wy1 : 0.f;
  float fx0 = ((unsigned)x0 < (unsigned)WW) ? (1.f - wx1) : 0.f;
  float fx1 = ((unsigned)(x0 + 1) < (unsigned)WW) ? wx1 : 0.f;
  g.f00 = fy0 * fx0; g.f01 = fy0 * fx1;
  g.f10 = fy1 * fx0; g.f11 = fy1 * fx1;
  int r0 = min(max(y0, 0), HH - 1), r1 = min(max(y0 + 1, 0), HH - 1);
  int q0 = min(max(x0, 0), WW - 1), q1 = min(max(x0 + 1, 0), WW - 1);
  g.o00 = (r0 * WW + q0) * C1; g.o01 = (r0 * WW + q1) * C1;
  g.o10 = (r1 * WW + q0) * C1; g.o11 = (r1 * WW + q1) * C1;
  return g;
}

__global__ __launch_bounds__(256) void dconv_mfma_kernel(
    const ushort* __restrict__ xt, const float* __restrict__ offs,
    const ushort* __restrict__ wbf, const float* __restrict__ bias,
    float* __restrict__ out) {
  const int bid = blockIdx.x;                    // 0..1599; bid%8 = b%8 (XCD/batch L2 locality)
  const int b = bid & 15;
  const int tile = bid >> 4;                     // 0..99
  const int h0 = (tile / 5) * 4;
  const int w0 = (tile % 5) * 16;
  const int tid = threadIdx.x;
  const int lane = tid & 63;
  const int wave = tid >> 6;
  const int q = lane >> 4, c15 = lane & 15;
  const int spos = wave * 16 + c15;

  __shared__ float4 crd[9][64];                  // 9216 B, wave-local use
  __shared__ ushort w_buf[4][4096];              // 32 KB, wave-PRIVATE 8 KB each

  const ushort* xtb = xt + (size_t)b * HWSZ * C1;

  // ---- Phase A: coords (writer and readers in the SAME wave; DS ops from a
  // wave complete in order -> no barrier needed)
  {
    const int ho = h0 + wave, wo = w0 + c15;
    const float* obp = offs + (size_t)b * 18 * HWSZ + ho * WW + wo;
    #pragma unroll
    for (int p = 0; p < 9; ++p) {
      if ((p & 3) == q) {
        float dy = obp[(size_t)(2 * p) * HWSZ];
        float dx = obp[(size_t)(2 * p + 1) * HWSZ];
        float py = (float)(ho - 1 + p / 3) + dy;
        float px = (float)(wo - 1 + p % 3) + dx;
        float y0f = floorf(py), x0f = floorf(px);
        crd[p][spos] = make_float4(y0f, x0f, py - y0f, px - x0f);
      }
    }
  }

  // stage chunk kt's weights (8 KB, 8 vmem ops) into THIS wave's buffer
  auto stage = [&](int kt) {
    #pragma unroll
    for (int j = 0; j < 8; ++j)
      gload_lds16(wbf + (size_t)kt * 4096 + (j * 64 + lane) * 8,
                  &w_buf[wave][j * 512]);
  };

  auto gload = [&](const Geo& gg, int c0,
                   uint4& r00, uint4& r01, uint4& r10, uint4& r11) {
    const ushort* cp = xtb + c0 + q * 8;
    r00 = *(const uint4*)(cp + gg.o00);
    r01 = *(const uint4*)(cp + gg.o01);
    r10 = *(const uint4*)(cp + gg.o10);
    r11 = *(const uint4*)(cp + gg.o11);
  };

  f32x4 acc[8];
  #pragma unroll
  for (int mt = 0; mt < 8; mt++) acc[mt] = (f32x4){0.f, 0.f, 0.f, 0.f};

  Geo gA = make_geo(crd[0][spos]);               // geo for current bilinear
  Geo gB = gA;                                   // geo for gather issue
  uint4 ca00, ca01, ca10, ca11;                  // chunk i   corners
  uint4 na00, na01, na10, na11;                  // chunk i+1 corners

  auto bilinear = [&](PkU& pk) {
    CornU u00, u01, u10, u11;
    u00.v = ca00; u01.v = ca01; u10.v = ca10; u11.v = ca11;
    #pragma unroll
    for (int jw = 0; jw < 4; ++jw) {
      float ol = gA.f00 * bfu_lo(u00.d[jw]);
      float oh = gA.f00 * bfu_hi(u00.d[jw]);
      ol = fmaf(gA.f01, bfu_lo(u01.d[jw]), ol);
      oh = fmaf(gA.f01, bfu_hi(u01.d[jw]), oh);
      ol = fmaf(gA.f10, bfu_lo(u10.d[jw]), ol);
      oh = fmaf(gA.f10, bfu_hi(u10.d[jw]), oh);
      ol = fmaf(gA.f11, bfu_lo(u11.d[jw]), ol);
      oh = fmaf(gA.f11, bfu_hi(u11.d[jw]), oh);
      pk.d[jw] = cvtpk(ol, oh);
    }
  };

  // ---- prologue (pinned vmem order): gathers(0) | stage(0) | gathers(1)
  gload(gA, 0, ca00, ca01, ca10, ca11);
  asm volatile("" ::: "memory");
  stage(0);
  asm volatile("" ::: "memory");
  gload(gA, 32, na00, na01, na10, na11);

  #pragma unroll 2
  for (int i = 0; i < 34; ++i) {
    if ((i & 3) == 0 && i) gA = gB;              // advance bilinear geometry

    PkU pk;
    bilinear(pk);

    // retire stage(i) (and gathers(i)); keep gathers(i+1) in flight
    asm volatile("s_waitcnt vmcnt(4)" ::: "memory");
    __builtin_amdgcn_sched_barrier(0);
    #pragma unroll
    for (int mt = 0; mt < 8; mt++) {
      bf16x8 afrag = *(const bf16x8*)&w_buf[wave][(q * 128 + mt * 16 + c15) * 8];
      acc[mt] = __builtin_amdgcn_mfma_f32_16x16x32_bf16(afrag, pk.h, acc[mt], 0, 0, 0);
    }

    // afrag ds_reads have landed in VGPRs; safe to overwrite the buffer
    asm volatile("s_waitcnt lgkmcnt(0)" ::: "memory");
    __builtin_amdgcn_sched_barrier(0);
    stage(i + 1);
    asm volatile("" ::: "memory");               // pin: stage before gathers

    ca00 = na00; ca01 = na01; ca10 = na10; ca11 = na11;
    if (((i + 2) & 3) == 0) gB = make_geo(crd[(i + 2) >> 2][spos]);
    gload(gB, ((i + 2) & 3) << 5, na00, na01, na10, na11);
  }

  // ---- peel i = 34 (no gathers(36))
  {
    PkU pk;
    bilinear(pk);                                // chunk 34 (gA set at i=32)
    asm volatile("s_waitcnt vmcnt(4)" ::: "memory");   // queue: stage(34)[8], g(35)[4]
    __builtin_amdgcn_sched_barrier(0);
    #pragma unroll
    for (int mt = 0; mt < 8; mt++) {
      bf16x8 afrag = *(const bf16x8*)&w_buf[wave][(q * 128 + mt * 16 + c15) * 8];
      acc[mt] = __builtin_amdgcn_mfma_f32_16x16x32_bf16(afrag, pk.h, acc[mt], 0, 0, 0);
    }
    asm volatile("s_waitcnt lgkmcnt(0)" ::: "memory");
    __builtin_amdgcn_sched_barrier(0);
    stage(35);
    asm volatile("" ::: "memory");
    ca00 = na00; ca01 = na01; ca10 = na10; ca11 = na11;
  }

  // ---- peel i = 35 (final; drain)
  {
    PkU pk;
    bilinear(pk);                                // chunk 35
    asm volatile("s_waitcnt vmcnt(0)" ::: "memory");   // retire stage(35)
    __builtin_amdgcn_sched_barrier(0);
    #pragma unroll
    for (int mt = 0; mt < 8; mt++) {
      bf16x8 afrag = *(const bf16x8*)&w_buf[wave][(q * 128 + mt * 16 + c15) * 8];
      acc[mt] = __builtin_amdgcn_mfma_f32_16x16x32_bf16(afrag, pk.h, acc[mt], 0, 0, 0);
    }
  }

  // ---- epilogue
  {
    const int ho = h0 + wave, wo = w0 + c15;
    #pragma unroll
    for (int mt = 0; mt < 8; mt++) {
      #pragma unroll
      for (int r = 0; r < 4; r++) {
        int ch = mt * 16 + q * 4 + r;
        out[((size_t)b * C2 + ch) * HWSZ + ho * WW + wo] = acc[mt][r] + bias[ch];
      }
    }
  }
}

// ---------------------------------------------------------------------------
extern "C" void kernel_launch(void* const* d_in, const int* in_sizes, int n_in,
                              void* d_out, int out_size, void* d_ws, size_t ws_size,
                              hipStream_t stream) {
  const float* x    = (const float*)d_in[0];   // (16,128,80,80)
  const float* ow   = (const float*)d_in[1];   // (18,128,3,3)
  const float* ob   = (const float*)d_in[2];   // (18,)
  const float* wgt  = (const float*)d_in[3];   // (128,128,3,3)
  const float* bias = (const float*)d_in[4];   // (128,)
  float* out = (float*)d_out;                  // (16,128,80,80)

  // workspace layout (xt first for 16B alignment)
  ushort* xt   = (ushort*)d_ws;                          // 26.2 MB
  float*  offs = (float*)((char*)d_ws + 26214400);       // 7.37 MB
  ushort* wbf  = (ushort*)((char*)d_ws + 26214400 + 7372800);           // 288 KB
  ushort* wobf = (ushort*)((char*)d_ws + 26214400 + 7372800 + 294912);  // 72 KB

  xpose_prep_kernel<<<dim3(3920), dim3(256), 0, stream>>>(x, xt, wgt, ow, wbf, wobf);
  offset_mfma_kernel<<<dim3(1600), dim3(256), 0, stream>>>(xt, wobf, ob, offs);
  dconv_mfma_kernel<<<dim3(1600), dim3(256), 0, stream>>>(xt, offs, wbf, bias, out);
}

// Round 8
// 236.550 us; speedup vs baseline: 1.3035x; 1.3035x over previous
//
#include <hip/hip_runtime.h>

// Problem constants (B=16, C1=C2=128, H=W=80, K=3, pad=1, stride=1)
#define HH 80
#define WW 80
#define C1 128
#define C2 128
#define NB 16
#define HWSZ 6400      // 80*80
#define KKT 1152       // C1*9 (GEMM K, reordered as k' = p*128 + c)

typedef __attribute__((ext_vector_type(8))) short bf16x8;
typedef __attribute__((ext_vector_type(4))) float f32x4;

union PkU   { uint4 v; uint d[4]; bf16x8 h; };
union CornU { uint4 v; uint d[4]; };

__device__ inline ushort f2bf(float f) {
  unsigned u = __float_as_uint(f);
  return (ushort)((u + 0x7FFFu + ((u >> 16) & 1u)) >> 16);
}

// packed f32x2 -> bf16x2 (RNE, identical rounding to f2bf)
__device__ inline uint cvtpk(float lo, float hi) {
  uint r;
  asm("v_cvt_pk_bf16_f32 %0, %1, %2" : "=v"(r) : "v"(lo), "v"(hi));
  return r;
}
__device__ inline float bfu_lo(uint w) { return __uint_as_float(w << 16); }
__device__ inline float bfu_hi(uint w) { return __uint_as_float(w & 0xFFFF0000u); }

// async global->LDS, 16B per lane, LDS dest = wave-uniform base (+lane*16 by HW)
// NOTE: completion tracked by vmcnt; CALLER must s_waitcnt before ds_read.
__device__ inline void gload_lds16(const ushort* g, ushort* l) {
  __builtin_amdgcn_global_load_lds(
      (const __attribute__((address_space(1))) void*)g,
      (__attribute__((address_space(3))) void*)l, 16, 0, 0);
}

// ---------------------------------------------------------------------------
// Kernel A+B merged: transpose x -> xt (blocks 0..3199) and weight prep
// (blocks 3200..3919).
// ---------------------------------------------------------------------------
__global__ __launch_bounds__(256) void xpose_prep_kernel(
    const float* __restrict__ x, ushort* __restrict__ xt,
    const float* __restrict__ w, const float* __restrict__ ow,
    ushort* __restrict__ wbf, ushort* __restrict__ wobf) {
  __shared__ float ts[64][65];
  const int idx = blockIdx.x;
  const int tid = threadIdx.x;

  if (idx < 3200) {
    const int b = idx / 200;
    const int rem = idx % 200;
    const int c0 = (rem / 100) * 64;
    const int hw0 = (rem % 100) * 64;
    const int lane = tid & 63;

    #pragma unroll
    for (int it = 0; it < 16; it++) {
      int cl = (tid >> 6) + it * 4;
      ts[cl][lane] = x[((size_t)(b * C1 + c0 + cl)) * HWSZ + hw0 + lane];
    }
    __syncthreads();

    #pragma unroll
    for (int it = 0; it < 2; it++) {
      int u = tid + it * 256;
      int j = u >> 3, cg = u & 7;
      CornU pk;
      #pragma unroll
      for (int m = 0; m < 4; m++)
        pk.d[m] = cvtpk(ts[cg * 8 + 2 * m][j], ts[cg * 8 + 2 * m + 1][j]);
      *(uint4*)(xt + ((size_t)b * HWSZ + hw0 + j) * C1 + c0 + cg * 8) = pk.v;
    }
  } else {
    int o = (idx - 3200) * 256 + tid;            // 0..184319
    if (o < C2 * KKT) {
      int j  = o & 7;
      int ch = (o >> 3) & 127;
      int kt = o >> 12;
      int kg = (o >> 10) & 3;
      int kprime = kt * 32 + kg * 8 + j;
      int p = kprime >> 7;
      int c = kprime & 127;
      wbf[o] = f2bf(w[(size_t)ch * KKT + c * 9 + p]);
    } else {
      int o2 = o - C2 * KKT;
      int j  = o2 & 7;
      int ch = (o2 >> 3) & 31;
      int kt = o2 >> 10;
      int kg = (o2 >> 8) & 3;
      int kprime = kt * 32 + kg * 8 + j;
      int p = kprime >> 7;
      int c = kprime & 127;
      wobf[o2] = (ch < 18) ? f2bf(ow[(size_t)ch * KKT + c * 9 + p]) : (ushort)0;
    }
  }
}

// ---------------------------------------------------------------------------
// Kernel C: offset conv (round-0 verbatim — known-good, ~37 us).
// ---------------------------------------------------------------------------
__global__ __launch_bounds__(256) void offset_mfma_kernel(
    const ushort* __restrict__ xt, const ushort* __restrict__ wobf,
    const float* __restrict__ ob, float* __restrict__ offs) {
  const int bid = blockIdx.x;                    // 0..1599
  const int b = bid & 15;
  const int tile = bid >> 4;                     // 0..99
  const int h0 = (tile / 5) * 4;
  const int w0 = (tile % 5) * 16;
  const int tid = threadIdx.x;
  const int lane = tid & 63;
  const int wave = tid >> 6;
  const int pl = lane & 15, cg = lane >> 4;
  const int spos = wave * 16 + pl;

  __shared__ ushort s_t[4][64][8];               // 4 KB
  __shared__ ushort w_t[4][32][8];               // 2 KB

  f32x4 acc0 = {0.f, 0.f, 0.f, 0.f}, acc1 = {0.f, 0.f, 0.f, 0.f};
  const ushort* xtb = xt + (size_t)b * HWSZ * C1;

  auto shifted_load = [&](int kt) -> uint4 {
    const int p = kt >> 2, c0 = (kt & 3) << 5;
    const int row = h0 + (spos >> 4) + (p / 3) - 1;
    const int col = w0 + (spos & 15) + (p % 3) - 1;
    uint4 v = {0u, 0u, 0u, 0u};
    if ((unsigned)row < (unsigned)HH && (unsigned)col < (unsigned)WW)
      v = *(const uint4*)(xtb + ((size_t)row * WW + col) * C1 + c0 + cg * 8);
    return v;
  };

  uint4 cv = shifted_load(0);
  uint4 cw = {0u, 0u, 0u, 0u};
  if (tid < 128) cw = ((const uint4*)wobf)[tid];

  #pragma unroll 4
  for (int kt = 0; kt < 36; ++kt) {
    uint4 nv = {0u, 0u, 0u, 0u}, nw = {0u, 0u, 0u, 0u};
    if (kt < 35) {
      nv = shifted_load(kt + 1);
      if (tid < 128) nw = ((const uint4*)(wobf + (size_t)(kt + 1) * 1024))[tid];
    }

    __syncthreads();
    ((uint4*)s_t)[cg * 64 + spos] = cv;
    if (tid < 128) ((uint4*)w_t)[tid] = cw;
    __syncthreads();

    const int q = lane >> 4, c15 = lane & 15;
    bf16x8 bfrag = *(const bf16x8*)&s_t[q][wave * 16 + c15][0];
    bf16x8 a0 = *(const bf16x8*)&w_t[q][c15][0];
    bf16x8 a1 = *(const bf16x8*)&w_t[q][16 + c15][0];
    acc0 = __builtin_amdgcn_mfma_f32_16x16x32_bf16(a0, bfrag, acc0, 0, 0, 0);
    acc1 = __builtin_amdgcn_mfma_f32_16x16x32_bf16(a1, bfrag, acc1, 0, 0, 0);

    cv = nv; cw = nw;
  }

  {
    const int q = lane >> 4, c15 = lane & 15;
    const int ho = h0 + wave, wo = w0 + c15;
    #pragma unroll
    for (int r = 0; r < 4; r++) {
      int ch = q * 4 + r;
      if (ch < 18)
        offs[((size_t)b * 18 + ch) * HWSZ + ho * WW + wo] = acc0[r] + ob[ch];
      int ch1 = 16 + q * 4 + r;
      if (ch1 < 18)
        offs[((size_t)b * 18 + ch1) * HWSZ + ho * WW + wo] = acc1[r] + ob[ch1];
    }
  }
}

// ---------------------------------------------------------------------------
// Kernel D: REQUEST-MINIMIZED per-p gathering.
// Theory: time ~ TCP line-requests.  Old scheme: per chunk, 4 corner gathers
// read 16 positions x 64B (half a 128B line each, re-touched by the next
// chunk).  New scheme: per kernel-position p, gather each corner's FULL 256B
// record with fully-used 128B lines (lane = 16B c-slice, 16 lanes/position,
// 4 positions/instr), bilinear in registers, redistribute sampled tile to
// MFMA B-frag layout via a wave-private XOR-swizzled LDS buffer.
//   gather reqs/wave-p: 256 -> 128;  stage reqs halve (per-p, 32KB single buf,
//   wave w stages chunk w);  barriers 36 -> 18, NONE drain the gathers
//   (raw s_barrier; hand vmcnt(16) retires stage(p) keeping g(p+1) in flight).
// ---------------------------------------------------------------------------
struct Geo { float f00, f01, f10, f11; int o00, o01, o10, o11; };

__device__ inline Geo make_geo(float4 cd) {
  Geo g;
  int y0 = (int)cd.x, x0 = (int)cd.y;
  float wy1 = cd.z, wx1 = cd.w;
  float fy0 = ((unsigned)y0 < (unsigned)HH) ? (1.f - wy1) : 0.f;
  float fy1 = ((unsigned)(y0 + 1) < (unsigned)HH) ? wy1 : 0.f;
  float fx0 = ((unsigned)x0 < (unsigned)WW) ? (1.f - wx1) : 0.f;
  float fx1 = ((unsigned)(x0 + 1) < (unsigned)WW) ? wx1 : 0.f;
  g.f00 = fy0 * fx0; g.f01 = fy0 * fx1;
  g.f10 = fy1 * fx0; g.f11 = fy1 * fx1;
  int r0 = min(max(y0, 0), HH - 1), r1 = min(max(y0 + 1, 0), HH - 1);
  int q0 = min(max(x0, 0), WW - 1), q1 = min(max(x0 + 1, 0), WW - 1);
  g.o00 = (r0 * WW + q0) * C1; g.o01 = (r0 * WW + q1) * C1;
  g.o10 = (r1 * WW + q0) * C1; g.o11 = (r1 * WW + q1) * C1;
  return g;
}

__global__ __launch_bounds__(256) void dconv_mfma_kernel(
    const ushort* __restrict__ xt, const float* __restrict__ offs,
    const ushort* __restrict__ wbf, const float* __restrict__ bias,
    float* __restrict__ out) {
  const int bid = blockIdx.x;                    // 0..1599; bid%8 = b%8 (XCD/batch)
  const int b = bid & 15;
  const int tile = bid >> 4;                     // 0..99
  const int h0 = (tile / 5) * 4;
  const int w0 = (tile % 5) * 16;
  const int tid = threadIdx.x;
  const int lane = tid & 63;
  const int wave = tid >> 6;
  const int q = lane >> 4, c15 = lane & 15;
  const int spos = wave * 16 + c15;

  __shared__ float4 crd[9][64];                  // 9216 B (same-wave use only)
  __shared__ ushort w_pbuf[4][4096];             // 32 KB: chunk kk of current p
  __shared__ ushort smp[4][16][128];             // 16 KB: [wave][pos][ch], swizzled

  const ushort* xtb = xt + (size_t)b * HWSZ * C1;

  // ---- Phase A: coords (writer and readers are the SAME wave; DS in-order)
  {
    const int ho = h0 + wave, wo = w0 + c15;
    const float* obp = offs + (size_t)b * 18 * HWSZ + ho * WW + wo;
    #pragma unroll
    for (int p = 0; p < 9; ++p) {
      if ((p & 3) == q) {
        float dy = obp[(size_t)(2 * p) * HWSZ];
        float dx = obp[(size_t)(2 * p + 1) * HWSZ];
        float py = (float)(ho - 1 + p / 3) + dy;
        float px = (float)(wo - 1 + p % 3) + dx;
        float y0f = floorf(py), x0f = floorf(px);
        crd[p][spos] = make_float4(y0f, x0f, py - y0f, px - x0f);
      }
    }
  }

  // per-lane gather identity: jp = sub-position (0..3), s = 16B channel-slice
  const int jp = lane >> 4;
  const int s  = lane & 15;

  float4 fw[4];          // bilinear corner weights for this wave-lane's 4 pos
  uint4  cr[4][4];       // gathered corners: [jj][corner], 16B each

  // gather corners for kernel-position p: 16 instrs, each 4 pos x full lines
  auto issue_p = [&](int p) {
    #pragma unroll
    for (int jj = 0; jj < 4; ++jj) {
      Geo gg = make_geo(crd[p][wave * 16 + 4 * jj + jp]);
      fw[jj] = make_float4(gg.f00, gg.f01, gg.f10, gg.f11);
      const ushort* cp = xtb + s * 8;
      cr[jj][0] = *(const uint4*)(cp + gg.o00);
      cr[jj][1] = *(const uint4*)(cp + gg.o01);
      cr[jj][2] = *(const uint4*)(cp + gg.o10);
      cr[jj][3] = *(const uint4*)(cp + gg.o11);
    }
  };

  // stage all 4 chunks of p's weights; wave w stages chunk kk=w (8 instrs)
  auto stage_p = [&](int p) {
    #pragma unroll
    for (int j = 0; j < 8; ++j)
      gload_lds16(wbf + ((size_t)(4 * p + wave)) * 4096 + (j * 64 + lane) * 8,
                  w_pbuf[wave] + j * 512);
  };

  // bilinear-combine cr with fw; write sampled 16B to swizzled smp
  auto bilinear_write = [&]() {
    #pragma unroll
    for (int jj = 0; jj < 4; ++jj) {
      const int pos = 4 * jj + jp;
      CornU u0, u1, u2, u3;
      PkU pk;
      u0.v = cr[jj][0]; u1.v = cr[jj][1]; u2.v = cr[jj][2]; u3.v = cr[jj][3];
      const float f00 = fw[jj].x, f01 = fw[jj].y, f10 = fw[jj].z, f11 = fw[jj].w;
      #pragma unroll
      for (int d = 0; d < 4; ++d) {
        float ol = f00 * bfu_lo(u0.d[d]);
        float oh = f00 * bfu_hi(u0.d[d]);
        ol = fmaf(f01, bfu_lo(u1.d[d]), ol);
        oh = fmaf(f01, bfu_hi(u1.d[d]), oh);
        ol = fmaf(f10, bfu_lo(u2.d[d]), ol);
        oh = fmaf(f10, bfu_hi(u2.d[d]), oh);
        ol = fmaf(f11, bfu_lo(u3.d[d]), ol);
        oh = fmaf(f11, bfu_hi(u3.d[d]), oh);
        pk.d[d] = cvtpk(ol, oh);
      }
      char* wp = (char*)&smp[wave][pos][0] + ((s * 16) ^ ((pos & 7) << 4));
      *(uint4*)wp = pk.v;
    }
  };

  f32x4 acc[8];
  #pragma unroll
  for (int mt = 0; mt < 8; mt++) acc[mt] = (f32x4){0.f, 0.f, 0.f, 0.f};

  // prologue: gathers for p=0 (crd ready: same-wave DS ordering)
  issue_p(0);
  asm volatile("" ::: "memory");                 // pin g(0) oldest

  #pragma unroll 1
  for (int p = 0; p < 9; ++p) {
    // barrier1: everyone done reading w_pbuf of p-1 (ds_reads consumed by
    // MFMAs => lgkm clean; raw barrier, NO vmcnt drain — g(p) stays in flight)
    asm volatile("s_waitcnt lgkmcnt(0)" ::: "memory");
    __builtin_amdgcn_s_barrier();

    stage_p(p);                                  // vmem order: stage(p)...
    asm volatile("" ::: "memory");

    bilinear_write();                            // consumes g(p) (auto-wait)

    if (p < 8) {
      issue_p(p + 1);                            // ...then g(p+1) youngest
      asm volatile("" ::: "memory");
      asm volatile("s_waitcnt vmcnt(16)" ::: "memory");  // retire stage(p) only
    } else {
      asm volatile("s_waitcnt vmcnt(0)" ::: "memory");
    }
    __builtin_amdgcn_sched_barrier(0);
    asm volatile("s_waitcnt lgkmcnt(0)" ::: "memory");   // smp writes done
    __builtin_amdgcn_s_barrier();                // barrier2: all stages landed

    // chunk-loop: 4 chunks of p, B-frag from swizzled smp, A-frags from w_pbuf
    #pragma unroll
    for (int kk = 0; kk < 4; ++kk) {
      const char* bp = (const char*)&smp[wave][c15][0] +
                       ((kk * 64 + q * 16) ^ ((c15 & 7) << 4));
      bf16x8 bfrag = *(const bf16x8*)bp;
      #pragma unroll
      for (int mt = 0; mt < 8; mt++) {
        bf16x8 afrag = *(const bf16x8*)&w_pbuf[kk][(q * 128 + mt * 16 + c15) * 8];
        acc[mt] = __builtin_amdgcn_mfma_f32_16x16x32_bf16(afrag, bfrag, acc[mt], 0, 0, 0);
      }
    }
  }

  // ---- epilogue
  {
    const int ho = h0 + wave, wo = w0 + c15;
    #pragma unroll
    for (int mt = 0; mt < 8; mt++) {
      #pragma unroll
      for (int r = 0; r < 4; r++) {
        int ch = mt * 16 + q * 4 + r;
        out[((size_t)b * C2 + ch) * HWSZ + ho * WW + wo] = acc[mt][r] + bias[ch];
      }
    }
  }
}

// ---------------------------------------------------------------------------
extern "C" void kernel_launch(void* const* d_in, const int* in_sizes, int n_in,
                              void* d_out, int out_size, void* d_ws, size_t ws_size,
                              hipStream_t stream) {
  const float* x    = (const float*)d_in[0];   // (16,128,80,80)
  const float* ow   = (const float*)d_in[1];   // (18,128,3,3)
  const float* ob   = (const float*)d_in[2];   // (18,)
  const float* wgt  = (const float*)d_in[3];   // (128,128,3,3)
  const float* bias = (const float*)d_in[4];   // (128,)
  float* out = (float*)d_out;                  // (16,128,80,80)

  // workspace layout (xt first for 16B alignment)
  ushort* xt   = (ushort*)d_ws;                          // 26.2 MB
  float*  offs = (float*)((char*)d_ws + 26214400);       // 7.37 MB
  ushort* wbf  = (ushort*)((char*)d_ws + 26214400 + 7372800);           // 288 KB
  ushort* wobf = (ushort*)((char*)d_ws + 26214400 + 7372800 + 294912);  // 72 KB

  xpose_prep_kernel<<<dim3(3920), dim3(256), 0, stream>>>(x, xt, wgt, ow, wbf, wobf);
  offset_mfma_kernel<<<dim3(1600), dim3(256), 0, stream>>>(xt, wobf, ob, offs);
  dconv_mfma_kernel<<<dim3(1600), dim3(256), 0, stream>>>(xt, offs, wbf, bias, out);
}

// Round 9
// 219.774 us; speedup vs baseline: 1.4030x; 1.0763x over previous
//
#include <hip/hip_runtime.h>

// Problem constants (B=16, C1=C2=128, H=W=80, K=3, pad=1, stride=1)
#define HH 80
#define WW 80
#define C1 128
#define C2 128
#define NB 16
#define HWSZ 6400      // 80*80
#define KKT 1152       // C1*9 (GEMM K, reordered as k' = p*128 + c)

typedef __attribute__((ext_vector_type(8))) short bf16x8;
typedef __attribute__((ext_vector_type(4))) float f32x4;

union PkU   { uint4 v; uint d[4]; bf16x8 h; };
union CornU { uint4 v; uint d[4]; };

__device__ inline ushort f2bf(float f) {
  unsigned u = __float_as_uint(f);
  return (ushort)((u + 0x7FFFu + ((u >> 16) & 1u)) >> 16);
}

// packed f32x2 -> bf16x2 (RNE, identical rounding to f2bf)
__device__ inline uint cvtpk(float lo, float hi) {
  uint r;
  asm("v_cvt_pk_bf16_f32 %0, %1, %2" : "=v"(r) : "v"(lo), "v"(hi));
  return r;
}
__device__ inline float bfu_lo(uint w) { return __uint_as_float(w << 16); }
__device__ inline float bfu_hi(uint w) { return __uint_as_float(w & 0xFFFF0000u); }

// async global->LDS, 16B per lane, LDS dest = wave-uniform base (+lane*16 by HW)
// NOTE: completion tracked by vmcnt; CALLER must s_waitcnt before ds_read.
// Global SOURCE address is per-lane (m173): swizzles go on the source side.
__device__ inline void gload_lds16(const ushort* g, ushort* l) {
  __builtin_amdgcn_global_load_lds(
      (const __attribute__((address_space(1))) void*)g,
      (__attribute__((address_space(3))) void*)l, 16, 0, 0);
}

// ---------------------------------------------------------------------------
// Kernel A+B merged: transpose x -> xt (blocks 0..3199), weight prep
// (blocks 3200..3919), and 256B zero page for OOB gathers (block 3200).
// ---------------------------------------------------------------------------
__global__ __launch_bounds__(256) void xpose_prep_kernel(
    const float* __restrict__ x, ushort* __restrict__ xt,
    const float* __restrict__ w, const float* __restrict__ ow,
    ushort* __restrict__ wbf, ushort* __restrict__ wobf,
    ushort* __restrict__ zpad) {
  __shared__ float ts[64][65];
  const int idx = blockIdx.x;
  const int tid = threadIdx.x;

  if (idx < 3200) {
    const int b = idx / 200;
    const int rem = idx % 200;
    const int c0 = (rem / 100) * 64;
    const int hw0 = (rem % 100) * 64;
    const int lane = tid & 63;

    #pragma unroll
    for (int it = 0; it < 16; it++) {
      int cl = (tid >> 6) + it * 4;
      ts[cl][lane] = x[((size_t)(b * C1 + c0 + cl)) * HWSZ + hw0 + lane];
    }
    __syncthreads();

    #pragma unroll
    for (int it = 0; it < 2; it++) {
      int u = tid + it * 256;
      int j = u >> 3, cg = u & 7;
      CornU pk;
      #pragma unroll
      for (int m = 0; m < 4; m++)
        pk.d[m] = cvtpk(ts[cg * 8 + 2 * m][j], ts[cg * 8 + 2 * m + 1][j]);
      *(uint4*)(xt + ((size_t)b * HWSZ + hw0 + j) * C1 + c0 + cg * 8) = pk.v;
    }
  } else {
    if (idx == 3200 && tid < 16) {
      uint4 z = {0u, 0u, 0u, 0u};
      ((uint4*)zpad)[tid] = z;                   // 256B zero page
    }
    int o = (idx - 3200) * 256 + tid;            // 0..184319
    if (o < C2 * KKT) {
      int j  = o & 7;
      int ch = (o >> 3) & 127;
      int kt = o >> 12;
      int kg = (o >> 10) & 3;
      int kprime = kt * 32 + kg * 8 + j;
      int p = kprime >> 7;
      int c = kprime & 127;
      wbf[o] = f2bf(w[(size_t)ch * KKT + c * 9 + p]);
    } else {
      int o2 = o - C2 * KKT;
      int j  = o2 & 7;
      int ch = (o2 >> 3) & 31;
      int kt = o2 >> 10;
      int kg = (o2 >> 8) & 3;
      int kprime = kt * 32 + kg * 8 + j;
      int p = kprime >> 7;
      int c = kprime & 127;
      wobf[o2] = (ch < 18) ? f2bf(ow[(size_t)ch * KKT + c * 9 + p]) : (ushort)0;
    }
  }
}

// ---------------------------------------------------------------------------
// Kernel C v2: offset conv, REQUEST-MINIMIZED per-p style (mirrors the
// verified r8 dconv structure, simpler: no bilinear).
//  - per p: regular-grid records go DIRECTLY global->LDS into the B-frag
//    buffer (dest linear in lane: pos*256+s*16 == lane*16); bank swizzle is
//    applied on the per-lane SOURCE slice (s ^ (pos&7), involution).
//  - full 256B records, fully-used 128B lines: 32 gather lines/wave-p vs
//    ~64 half-used before (the old c0=0/32 chunks re-requested each line 2x).
//  - weights: wave stages chunk kk=wave of wobf[p] (2 KB) -> shared w_obuf.
//  - ONE vmcnt(0) drain per p (9 total vs 72); 24 KB LDS -> ~6 blocks/CU,
//    TLP hides the drains.  Zero VALU sampling (no bilinear, no cvtpk).
// ---------------------------------------------------------------------------
__global__ __launch_bounds__(256) void offset_mfma_kernel(
    const ushort* __restrict__ xt, const ushort* __restrict__ wobf,
    const ushort* __restrict__ zpad, const float* __restrict__ ob,
    float* __restrict__ offs) {
  const int bid = blockIdx.x;                    // 0..1599
  const int b = bid & 15;
  const int tile = bid >> 4;                     // 0..99
  const int h0 = (tile / 5) * 4;
  const int w0 = (tile % 5) * 16;
  const int tid = threadIdx.x;
  const int lane = tid & 63;
  const int wave = tid >> 6;
  const int q = lane >> 4, c15 = lane & 15;      // q = k-group / jp; c15 = pos / slice

  __shared__ ushort w_obuf[4][1024];             // 8 KB: wobf chunks of current p
  __shared__ ushort smp[4][16][128];             // 16 KB: [wave][pos][ch], src-swizzled

  const ushort* xtb = xt + (size_t)b * HWSZ * C1;
  f32x4 acc0 = {0.f, 0.f, 0.f, 0.f}, acc1 = {0.f, 0.f, 0.f, 0.f};

  #pragma unroll 1
  for (int p = 0; p < 9; ++p) {
    // previous p's LDS reads are done everywhere before overwrite
    asm volatile("s_waitcnt lgkmcnt(0)" ::: "memory");
    __builtin_amdgcn_s_barrier();

    // stage wobf[4p+wave] (2 KB) into w_obuf[wave]  (2 vmem instrs)
    #pragma unroll
    for (int j = 0; j < 2; ++j)
      gload_lds16(wobf + (size_t)(4 * p + wave) * 1024 + (j * 64 + lane) * 8,
                  &w_obuf[wave][j * 512]);

    // gather this wave's 16 regular-grid records into smp[wave] (4 instrs)
    {
      const int row = h0 + wave + p / 3 - 1;
      #pragma unroll
      for (int jj = 0; jj < 4; ++jj) {
        const int pos = 4 * jj + q;              // q doubles as jp
        const int col = w0 + pos + p % 3 - 1;
        const int sl = c15 ^ (pos & 7);          // source-side bank swizzle
        const ushort* src =
            ((unsigned)row < (unsigned)HH && (unsigned)col < (unsigned)WW)
                ? xtb + ((size_t)row * WW + col) * C1 + sl * 8
                : zpad + sl * 8;
        gload_lds16(src, &smp[wave][4 * jj][0]);
      }
    }

    asm volatile("s_waitcnt vmcnt(0)" ::: "memory");
    __builtin_amdgcn_s_barrier();                // stages + gathers landed

    // mini-GEMM: 4 chunks x {a0,a1}; B-frag slice (4kk+q) of pos c15
    #pragma unroll
    for (int kk = 0; kk < 4; ++kk) {
      bf16x8 bfrag = *(const bf16x8*)
          &smp[wave][c15][(((4 * kk + q) ^ (c15 & 7)) * 8)];
      bf16x8 a0 = *(const bf16x8*)&w_obuf[kk][(q * 32 + c15) * 8];
      bf16x8 a1 = *(const bf16x8*)&w_obuf[kk][(q * 32 + 16 + c15) * 8];
      acc0 = __builtin_amdgcn_mfma_f32_16x16x32_bf16(a0, bfrag, acc0, 0, 0, 0);
      acc1 = __builtin_amdgcn_mfma_f32_16x16x32_bf16(a1, bfrag, acc1, 0, 0, 0);
    }
  }

  // epilogue: D col = c15 (pos), row = q*4+r (ch)   (r0-identical)
  {
    const int ho = h0 + wave, wo = w0 + c15;
    #pragma unroll
    for (int r = 0; r < 4; r++) {
      int ch = q * 4 + r;
      if (ch < 18)
        offs[((size_t)b * 18 + ch) * HWSZ + ho * WW + wo] = acc0[r] + ob[ch];
      int ch1 = 16 + q * 4 + r;
      if (ch1 < 18)
        offs[((size_t)b * 18 + ch1) * HWSZ + ho * WW + wo] = acc1[r] + ob[ch1];
    }
  }
}

// ---------------------------------------------------------------------------
// Kernel D: REQUEST-MINIMIZED per-p gathering (r8 verbatim — FROZEN winner).
// ---------------------------------------------------------------------------
struct Geo { float f00, f01, f10, f11; int o00, o01, o10, o11; };

__device__ inline Geo make_geo(float4 cd) {
  Geo g;
  int y0 = (int)cd.x, x0 = (int)cd.y;
  float wy1 = cd.z, wx1 = cd.w;
  float fy0 = ((unsigned)y0 < (unsigned)HH) ? (1.f - wy1) : 0.f;
  float fy1 = ((unsigned)(y0 + 1) < (unsigned)HH) ? wy1 : 0.f;
  float fx0 = ((unsigned)x0 < (unsigned)WW) ? (1.f - wx1) : 0.f;
  float fx1 = ((unsigned)(x0 + 1) < (unsigned)WW) ? wx1 : 0.f;
  g.f00 = fy0 * fx0; g.f01 = fy0 * fx1;
  g.f10 = fy1 * fx0; g.f11 = fy1 * fx1;
  int r0 = min(max(y0, 0), HH - 1), r1 = min(max(y0 + 1, 0), HH - 1);
  int q0 = min(max(x0, 0), WW - 1), q1 = min(max(x0 + 1, 0), WW - 1);
  g.o00 = (r0 * WW + q0) * C1; g.o01 = (r0 * WW + q1) * C1;
  g.o10 = (r1 * WW + q0) * C1; g.o11 = (r1 * WW + q1) * C1;
  return g;
}

__global__ __launch_bounds__(256) void dconv_mfma_kernel(
    const ushort* __restrict__ xt, const float* __restrict__ offs,
    const ushort* __restrict__ wbf, const float* __restrict__ bias,
    float* __restrict__ out) {
  const int bid = blockIdx.x;                    // 0..1599; bid%8 = b%8 (XCD/batch)
  const int b = bid & 15;
  const int tile = bid >> 4;                     // 0..99
  const int h0 = (tile / 5) * 4;
  const int w0 = (tile % 5) * 16;
  const int tid = threadIdx.x;
  const int lane = tid & 63;
  const int wave = tid >> 6;
  const int q = lane >> 4, c15 = lane & 15;
  const int spos = wave * 16 + c15;

  __shared__ float4 crd[9][64];                  // 9216 B (same-wave use only)
  __shared__ ushort w_pbuf[4][4096];             // 32 KB: chunk kk of current p
  __shared__ ushort smp[4][16][128];             // 16 KB: [wave][pos][ch], swizzled

  const ushort* xtb = xt + (size_t)b * HWSZ * C1;

  // ---- Phase A: coords (writer and readers are the SAME wave; DS in-order)
  {
    const int ho = h0 + wave, wo = w0 + c15;
    const float* obp = offs + (size_t)b * 18 * HWSZ + ho * WW + wo;
    #pragma unroll
    for (int p = 0; p < 9; ++p) {
      if ((p & 3) == q) {
        float dy = obp[(size_t)(2 * p) * HWSZ];
        float dx = obp[(size_t)(2 * p + 1) * HWSZ];
        float py = (float)(ho - 1 + p / 3) + dy;
        float px = (float)(wo - 1 + p % 3) + dx;
        float y0f = floorf(py), x0f = floorf(px);
        crd[p][spos] = make_float4(y0f, x0f, py - y0f, px - x0f);
      }
    }
  }

  // per-lane gather identity: jp = sub-position (0..3), s = 16B channel-slice
  const int jp = lane >> 4;
  const int s  = lane & 15;

  float4 fw[4];          // bilinear corner weights for this wave-lane's 4 pos
  uint4  cr[4][4];       // gathered corners: [jj][corner], 16B each

  // gather corners for kernel-position p: 16 instrs, each 4 pos x full lines
  auto issue_p = [&](int p) {
    #pragma unroll
    for (int jj = 0; jj < 4; ++jj) {
      Geo gg = make_geo(crd[p][wave * 16 + 4 * jj + jp]);
      fw[jj] = make_float4(gg.f00, gg.f01, gg.f10, gg.f11);
      const ushort* cp = xtb + s * 8;
      cr[jj][0] = *(const uint4*)(cp + gg.o00);
      cr[jj][1] = *(const uint4*)(cp + gg.o01);
      cr[jj][2] = *(const uint4*)(cp + gg.o10);
      cr[jj][3] = *(const uint4*)(cp + gg.o11);
    }
  };

  // stage all 4 chunks of p's weights; wave w stages chunk kk=w (8 instrs)
  auto stage_p = [&](int p) {
    #pragma unroll
    for (int j = 0; j < 8; ++j)
      gload_lds16(wbf + ((size_t)(4 * p + wave)) * 4096 + (j * 64 + lane) * 8,
                  w_pbuf[wave] + j * 512);
  };

  // bilinear-combine cr with fw; write sampled 16B to swizzled smp
  auto bilinear_write = [&]() {
    #pragma unroll
    for (int jj = 0; jj < 4; ++jj) {
      const int pos = 4 * jj + jp;
      CornU u0, u1, u2, u3;
      PkU pk;
      u0.v = cr[jj][0]; u1.v = cr[jj][1]; u2.v = cr[jj][2]; u3.v = cr[jj][3];
      const float f00 = fw[jj].x, f01 = fw[jj].y, f10 = fw[jj].z, f11 = fw[jj].w;
      #pragma unroll
      for (int d = 0; d < 4; ++d) {
        float ol = f00 * bfu_lo(u0.d[d]);
        float oh = f00 * bfu_hi(u0.d[d]);
        ol = fmaf(f01, bfu_lo(u1.d[d]), ol);
        oh = fmaf(f01, bfu_hi(u1.d[d]), oh);
        ol = fmaf(f10, bfu_lo(u2.d[d]), ol);
        oh = fmaf(f10, bfu_hi(u2.d[d]), oh);
        ol = fmaf(f11, bfu_lo(u3.d[d]), ol);
        oh = fmaf(f11, bfu_hi(u3.d[d]), oh);
        pk.d[d] = cvtpk(ol, oh);
      }
      char* wp = (char*)&smp[wave][pos][0] + ((s * 16) ^ ((pos & 7) << 4));
      *(uint4*)wp = pk.v;
    }
  };

  f32x4 acc[8];
  #pragma unroll
  for (int mt = 0; mt < 8; mt++) acc[mt] = (f32x4){0.f, 0.f, 0.f, 0.f};

  // prologue: gathers for p=0 (crd ready: same-wave DS ordering)
  issue_p(0);
  asm volatile("" ::: "memory");                 // pin g(0) oldest

  #pragma unroll 1
  for (int p = 0; p < 9; ++p) {
    // barrier1: everyone done reading w_pbuf of p-1 (ds_reads consumed by
    // MFMAs => lgkm clean; raw barrier, NO vmcnt drain — g(p) stays in flight)
    asm volatile("s_waitcnt lgkmcnt(0)" ::: "memory");
    __builtin_amdgcn_s_barrier();

    stage_p(p);                                  // vmem order: stage(p)...
    asm volatile("" ::: "memory");

    bilinear_write();                            // consumes g(p) (auto-wait)

    if (p < 8) {
      issue_p(p + 1);                            // ...then g(p+1) youngest
      asm volatile("" ::: "memory");
      asm volatile("s_waitcnt vmcnt(16)" ::: "memory");  // retire stage(p) only
    } else {
      asm volatile("s_waitcnt vmcnt(0)" ::: "memory");
    }
    __builtin_amdgcn_sched_barrier(0);
    asm volatile("s_waitcnt lgkmcnt(0)" ::: "memory");   // smp writes done
    __builtin_amdgcn_s_barrier();                // barrier2: all stages landed

    // chunk-loop: 4 chunks of p, B-frag from swizzled smp, A-frags from w_pbuf
    #pragma unroll
    for (int kk = 0; kk < 4; ++kk) {
      const char* bp = (const char*)&smp[wave][c15][0] +
                       ((kk * 64 + q * 16) ^ ((c15 & 7) << 4));
      bf16x8 bfrag = *(const bf16x8*)bp;
      #pragma unroll
      for (int mt = 0; mt < 8; mt++) {
        bf16x8 afrag = *(const bf16x8*)&w_pbuf[kk][(q * 128 + mt * 16 + c15) * 8];
        acc[mt] = __builtin_amdgcn_mfma_f32_16x16x32_bf16(afrag, bfrag, acc[mt], 0, 0, 0);
      }
    }
  }

  // ---- epilogue
  {
    const int ho = h0 + wave, wo = w0 + c15;
    #pragma unroll
    for (int mt = 0; mt < 8; mt++) {
      #pragma unroll
      for (int r = 0; r < 4; r++) {
        int ch = mt * 16 + q * 4 + r;
        out[((size_t)b * C2 + ch) * HWSZ + ho * WW + wo] = acc[mt][r] + bias[ch];
      }
    }
  }
}

// ---------------------------------------------------------------------------
extern "C" void kernel_launch(void* const* d_in, const int* in_sizes, int n_in,
                              void* d_out, int out_size, void* d_ws, size_t ws_size,
                              hipStream_t stream) {
  const float* x    = (const float*)d_in[0];   // (16,128,80,80)
  const float* ow   = (const float*)d_in[1];   // (18,128,3,3)
  const float* ob   = (const float*)d_in[2];   // (18,)
  const float* wgt  = (const float*)d_in[3];   // (128,128,3,3)
  const float* bias = (const float*)d_in[4];   // (128,)
  float* out = (float*)d_out;                  // (16,128,80,80)

  // workspace layout (xt first for 16B alignment)
  ushort* xt   = (ushort*)d_ws;                          // 26.2 MB
  float*  offs = (float*)((char*)d_ws + 26214400);       // 7.37 MB
  ushort* wbf  = (ushort*)((char*)d_ws + 26214400 + 7372800);           // 288 KB
  ushort* wobf = (ushort*)((char*)d_ws + 26214400 + 7372800 + 294912);  // 72 KB
  ushort* zpad = (ushort*)((char*)d_ws + 26214400 + 7372800 + 294912 + 73728); // 256 B zeros

  xpose_prep_kernel<<<dim3(3920), dim3(256), 0, stream>>>(x, xt, wgt, ow, wbf, wobf, zpad);
  offset_mfma_kernel<<<dim3(1600), dim3(256), 0, stream>>>(xt, wobf, zpad, ob, offs);
  dconv_mfma_kernel<<<dim3(1600), dim3(256), 0, stream>>>(xt, offs, wbf, bias, out);
}

// Round 10
// 216.096 us; speedup vs baseline: 1.4268x; 1.0170x over previous
//
#include <hip/hip_runtime.h>

// Problem constants (B=16, C1=C2=128, H=W=80, K=3, pad=1, stride=1)
#define HH 80
#define WW 80
#define C1 128
#define C2 128
#define NB 16
#define HWSZ 6400      // 80*80
#define KKT 1152       // C1*9 (GEMM K, reordered as k' = p*128 + c)

typedef __attribute__((ext_vector_type(8))) short bf16x8;
typedef __attribute__((ext_vector_type(4))) float f32x4;

union PkU   { uint4 v; uint d[4]; bf16x8 h; };
union CornU { uint4 v; uint d[4]; };

__device__ inline ushort f2bf(float f) {
  unsigned u = __float_as_uint(f);
  return (ushort)((u + 0x7FFFu + ((u >> 16) & 1u)) >> 16);
}

// packed f32x2 -> bf16x2 (RNE, identical rounding to f2bf)
__device__ inline uint cvtpk(float lo, float hi) {
  uint r;
  asm("v_cvt_pk_bf16_f32 %0, %1, %2" : "=v"(r) : "v"(lo), "v"(hi));
  return r;
}
__device__ inline float bfu_lo(uint w) { return __uint_as_float(w << 16); }
__device__ inline float bfu_hi(uint w) { return __uint_as_float(w & 0xFFFF0000u); }

// async global->LDS, 16B per lane, LDS dest = wave-uniform base (+lane*16 by HW)
// NOTE: completion tracked by vmcnt; CALLER must s_waitcnt before ds_read.
// Global SOURCE address is per-lane (m173): swizzles go on the source side.
__device__ inline void gload_lds16(const ushort* g, ushort* l) {
  __builtin_amdgcn_global_load_lds(
      (const __attribute__((address_space(1))) void*)g,
      (__attribute__((address_space(3))) void*)l, 16, 0, 0);
}

// ---------------------------------------------------------------------------
// Kernel A+B merged: transpose x -> xt (blocks 0..3199), weight prep
// (blocks 3200..3919), and 256B zero page for OOB gathers (block 3200).
// ---------------------------------------------------------------------------
__global__ __launch_bounds__(256) void xpose_prep_kernel(
    const float* __restrict__ x, ushort* __restrict__ xt,
    const float* __restrict__ w, const float* __restrict__ ow,
    ushort* __restrict__ wbf, ushort* __restrict__ wobf,
    ushort* __restrict__ zpad) {
  __shared__ float ts[64][65];
  const int idx = blockIdx.x;
  const int tid = threadIdx.x;

  if (idx < 3200) {
    const int b = idx / 200;
    const int rem = idx % 200;
    const int c0 = (rem / 100) * 64;
    const int hw0 = (rem % 100) * 64;
    const int lane = tid & 63;

    #pragma unroll
    for (int it = 0; it < 16; it++) {
      int cl = (tid >> 6) + it * 4;
      ts[cl][lane] = x[((size_t)(b * C1 + c0 + cl)) * HWSZ + hw0 + lane];
    }
    __syncthreads();

    #pragma unroll
    for (int it = 0; it < 2; it++) {
      int u = tid + it * 256;
      int j = u >> 3, cg = u & 7;
      CornU pk;
      #pragma unroll
      for (int m = 0; m < 4; m++)
        pk.d[m] = cvtpk(ts[cg * 8 + 2 * m][j], ts[cg * 8 + 2 * m + 1][j]);
      *(uint4*)(xt + ((size_t)b * HWSZ + hw0 + j) * C1 + c0 + cg * 8) = pk.v;
    }
  } else {
    if (idx == 3200 && tid < 16) {
      uint4 z = {0u, 0u, 0u, 0u};
      ((uint4*)zpad)[tid] = z;                   // 256B zero page
    }
    int o = (idx - 3200) * 256 + tid;            // 0..184319
    if (o < C2 * KKT) {
      int j  = o & 7;
      int ch = (o >> 3) & 127;
      int kt = o >> 12;
      int kg = (o >> 10) & 3;
      int kprime = kt * 32 + kg * 8 + j;
      int p = kprime >> 7;
      int c = kprime & 127;
      wbf[o] = f2bf(w[(size_t)ch * KKT + c * 9 + p]);
    } else {
      int o2 = o - C2 * KKT;
      int j  = o2 & 7;
      int ch = (o2 >> 3) & 31;
      int kt = o2 >> 10;
      int kg = (o2 >> 8) & 3;
      int kprime = kt * 32 + kg * 8 + j;
      int p = kprime >> 7;
      int c = kprime & 127;
      wobf[o2] = (ch < 18) ? f2bf(ow[(size_t)ch * KKT + c * 9 + p]) : (ushort)0;
    }
  }
}

// ---------------------------------------------------------------------------
// Kernel C (FUSED): phase 0 = r9's verified offset conv (per-p, request-
// minimized) writing to LDS obuf; phase A = coords from obuf (wave-local
// column -> no barrier); main = r8/r9 frozen per-p bilinear+MFMA loop.
// Buffer overlays keep LDS at 63 KB (2 blocks/CU, unchanged):
//   w_obuf (8 KB)  = first half of w_pbuf (32 KB)
//   smp (16 KB)    shared by phase 0 and main loop
// Eliminates: offset kernel launch, offs HBM round-trip, kernel-serial
// offset->dconv ordering (phase-0 of block n overlaps main of co-resident).
// ---------------------------------------------------------------------------
struct Geo { float f00, f01, f10, f11; int o00, o01, o10, o11; };

__device__ inline Geo make_geo(float4 cd) {
  Geo g;
  int y0 = (int)cd.x, x0 = (int)cd.y;
  float wy1 = cd.z, wx1 = cd.w;
  float fy0 = ((unsigned)y0 < (unsigned)HH) ? (1.f - wy1) : 0.f;
  float fy1 = ((unsigned)(y0 + 1) < (unsigned)HH) ? wy1 : 0.f;
  float fx0 = ((unsigned)x0 < (unsigned)WW) ? (1.f - wx1) : 0.f;
  float fx1 = ((unsigned)(x0 + 1) < (unsigned)WW) ? wx1 : 0.f;
  g.f00 = fy0 * fx0; g.f01 = fy0 * fx1;
  g.f10 = fy1 * fx0; g.f11 = fy1 * fx1;
  int r0 = min(max(y0, 0), HH - 1), r1 = min(max(y0 + 1, 0), HH - 1);
  int q0 = min(max(x0, 0), WW - 1), q1 = min(max(x0 + 1, 0), WW - 1);
  g.o00 = (r0 * WW + q0) * C1; g.o01 = (r0 * WW + q1) * C1;
  g.o10 = (r1 * WW + q0) * C1; g.o11 = (r1 * WW + q1) * C1;
  return g;
}

__global__ __launch_bounds__(256) void dconv_fused_kernel(
    const ushort* __restrict__ xt, const ushort* __restrict__ wobf,
    const ushort* __restrict__ zpad, const float* __restrict__ ob,
    const ushort* __restrict__ wbf, const float* __restrict__ bias,
    float* __restrict__ out) {
  const int bid = blockIdx.x;                    // 0..1599; bid%8 = b%8 (XCD/batch)
  const int b = bid & 15;
  const int tile = bid >> 4;                     // 0..99
  const int h0 = (tile / 5) * 4;
  const int w0 = (tile % 5) * 16;
  const int tid = threadIdx.x;
  const int lane = tid & 63;
  const int wave = tid >> 6;
  const int q = lane >> 4, c15 = lane & 15;
  const int spos = wave * 16 + c15;

  __shared__ float4 crd[9][64];                  // 9216 B (same-wave use only)
  __shared__ ushort w_pbuf[4][4096];             // 32 KB: weights of current p
  __shared__ ushort smp[4][16][128];             // 16 KB: [wave][pos][ch], swizzled
  __shared__ float  obuf[18][64];                // 4608 B: offset-conv result

  ushort (*w_obuf)[1024] = reinterpret_cast<ushort (*)[1024]>(&w_pbuf[0][0]);

  const ushort* xtb = xt + (size_t)b * HWSZ * C1;

  // ===================== Phase 0: offset conv (r9 body) =====================
  {
    f32x4 acc0 = {0.f, 0.f, 0.f, 0.f}, acc1 = {0.f, 0.f, 0.f, 0.f};

    #pragma unroll 1
    for (int p = 0; p < 9; ++p) {
      asm volatile("s_waitcnt lgkmcnt(0)" ::: "memory");
      __builtin_amdgcn_s_barrier();

      // stage wobf[4p+wave] (2 KB) into w_obuf[wave]  (2 vmem instrs)
      #pragma unroll
      for (int j = 0; j < 2; ++j)
        gload_lds16(wobf + (size_t)(4 * p + wave) * 1024 + (j * 64 + lane) * 8,
                    &w_obuf[wave][j * 512]);

      // gather this wave's 16 regular-grid records into smp[wave] (4 instrs)
      {
        const int row = h0 + wave + p / 3 - 1;
        #pragma unroll
        for (int jj = 0; jj < 4; ++jj) {
          const int pos = 4 * jj + q;            // q doubles as jp
          const int col = w0 + pos + p % 3 - 1;
          const int sl = c15 ^ (pos & 7);        // source-side bank swizzle
          const ushort* src =
              ((unsigned)row < (unsigned)HH && (unsigned)col < (unsigned)WW)
                  ? xtb + ((size_t)row * WW + col) * C1 + sl * 8
                  : zpad + sl * 8;
          gload_lds16(src, &smp[wave][4 * jj][0]);
        }
      }

      asm volatile("s_waitcnt vmcnt(0)" ::: "memory");
      __builtin_amdgcn_s_barrier();              // stages + gathers landed

      // mini-GEMM: 4 chunks x {a0,a1}; B-frag slice (4kk+q) of pos c15
      #pragma unroll
      for (int kk = 0; kk < 4; ++kk) {
        bf16x8 bfrag = *(const bf16x8*)
            &smp[wave][c15][(((4 * kk + q) ^ (c15 & 7)) * 8)];
        bf16x8 a0 = *(const bf16x8*)&w_obuf[kk][(q * 32 + c15) * 8];
        bf16x8 a1 = *(const bf16x8*)&w_obuf[kk][(q * 32 + 16 + c15) * 8];
        acc0 = __builtin_amdgcn_mfma_f32_16x16x32_bf16(a0, bfrag, acc0, 0, 0, 0);
        acc1 = __builtin_amdgcn_mfma_f32_16x16x32_bf16(a1, bfrag, acc1, 0, 0, 0);
      }
    }

    // epilogue -> LDS obuf (D col = c15 = pos, row = q*4+r = ch)
    #pragma unroll
    for (int r = 0; r < 4; r++) {
      int ch = q * 4 + r;                        // 0..15 all valid
      obuf[ch][spos] = acc0[r] + ob[ch];
    }
    if (q == 0) {
      obuf[16][spos] = acc1[0] + ob[16];
      obuf[17][spos] = acc1[1] + ob[17];
    }
  }

  // ===== Phase A: coords from obuf (same-wave column -> no barrier) =====
  {
    const int ho = h0 + wave, wo = w0 + c15;
    #pragma unroll
    for (int p = 0; p < 9; ++p) {
      if ((p & 3) == q) {
        float dy = obuf[2 * p][spos];
        float dx = obuf[2 * p + 1][spos];
        float py = (float)(ho - 1 + p / 3) + dy;
        float px = (float)(wo - 1 + p % 3) + dx;
        float y0f = floorf(py), x0f = floorf(px);
        crd[p][spos] = make_float4(y0f, x0f, py - y0f, px - x0f);
      }
    }
  }

  // ===================== Main loop: r8/r9 frozen structure ==================
  const int jp = lane >> 4;
  const int s  = lane & 15;

  float4 fw[4];          // bilinear corner weights for this wave-lane's 4 pos
  uint4  cr[4][4];       // gathered corners: [jj][corner], 16B each

  auto issue_p = [&](int p) {
    #pragma unroll
    for (int jj = 0; jj < 4; ++jj) {
      Geo gg = make_geo(crd[p][wave * 16 + 4 * jj + jp]);
      fw[jj] = make_float4(gg.f00, gg.f01, gg.f10, gg.f11);
      const ushort* cp = xtb + s * 8;
      cr[jj][0] = *(const uint4*)(cp + gg.o00);
      cr[jj][1] = *(const uint4*)(cp + gg.o01);
      cr[jj][2] = *(const uint4*)(cp + gg.o10);
      cr[jj][3] = *(const uint4*)(cp + gg.o11);
    }
  };

  auto stage_p = [&](int p) {
    #pragma unroll
    for (int j = 0; j < 8; ++j)
      gload_lds16(wbf + ((size_t)(4 * p + wave)) * 4096 + (j * 64 + lane) * 8,
                  w_pbuf[wave] + j * 512);
  };

  auto bilinear_write = [&]() {
    #pragma unroll
    for (int jj = 0; jj < 4; ++jj) {
      const int pos = 4 * jj + jp;
      CornU u0, u1, u2, u3;
      PkU pk;
      u0.v = cr[jj][0]; u1.v = cr[jj][1]; u2.v = cr[jj][2]; u3.v = cr[jj][3];
      const float f00 = fw[jj].x, f01 = fw[jj].y, f10 = fw[jj].z, f11 = fw[jj].w;
      #pragma unroll
      for (int d = 0; d < 4; ++d) {
        float ol = f00 * bfu_lo(u0.d[d]);
        float oh = f00 * bfu_hi(u0.d[d]);
        ol = fmaf(f01, bfu_lo(u1.d[d]), ol);
        oh = fmaf(f01, bfu_hi(u1.d[d]), oh);
        ol = fmaf(f10, bfu_lo(u2.d[d]), ol);
        oh = fmaf(f10, bfu_hi(u2.d[d]), oh);
        ol = fmaf(f11, bfu_lo(u3.d[d]), ol);
        oh = fmaf(f11, bfu_hi(u3.d[d]), oh);
        pk.d[d] = cvtpk(ol, oh);
      }
      char* wp = (char*)&smp[wave][pos][0] + ((s * 16) ^ ((pos & 7) << 4));
      *(uint4*)wp = pk.v;
    }
  };

  f32x4 acc[8];
  #pragma unroll
  for (int mt = 0; mt < 8; mt++) acc[mt] = (f32x4){0.f, 0.f, 0.f, 0.f};

  // prologue: gathers for p=0 (crd ready: same-wave DS ordering)
  issue_p(0);
  asm volatile("" ::: "memory");                 // pin g(0) oldest

  #pragma unroll 1
  for (int p = 0; p < 9; ++p) {
    // barrier1: everyone done reading w_pbuf/smp of previous phase (ds_reads
    // consumed by MFMAs => lgkm clean; raw barrier, NO vmcnt drain)
    asm volatile("s_waitcnt lgkmcnt(0)" ::: "memory");
    __builtin_amdgcn_s_barrier();

    stage_p(p);                                  // vmem order: stage(p)...
    asm volatile("" ::: "memory");

    bilinear_write();                            // consumes g(p) (auto-wait)

    if (p < 8) {
      issue_p(p + 1);                            // ...then g(p+1) youngest
      asm volatile("" ::: "memory");
      asm volatile("s_waitcnt vmcnt(16)" ::: "memory");  // retire stage(p) only
    } else {
      asm volatile("s_waitcnt vmcnt(0)" ::: "memory");
    }
    __builtin_amdgcn_sched_barrier(0);
    asm volatile("s_waitcnt lgkmcnt(0)" ::: "memory");   // smp writes done
    __builtin_amdgcn_s_barrier();                // barrier2: all stages landed

    // chunk-loop: 4 chunks of p, B-frag from swizzled smp, A-frags from w_pbuf
    #pragma unroll
    for (int kk = 0; kk < 4; ++kk) {
      const char* bp = (const char*)&smp[wave][c15][0] +
                       ((kk * 64 + q * 16) ^ ((c15 & 7) << 4));
      bf16x8 bfrag = *(const bf16x8*)bp;
      #pragma unroll
      for (int mt = 0; mt < 8; mt++) {
        bf16x8 afrag = *(const bf16x8*)&w_pbuf[kk][(q * 128 + mt * 16 + c15) * 8];
        acc[mt] = __builtin_amdgcn_mfma_f32_16x16x32_bf16(afrag, bfrag, acc[mt], 0, 0, 0);
      }
    }
  }

  // ---- epilogue
  {
    const int ho = h0 + wave, wo = w0 + c15;
    #pragma unroll
    for (int mt = 0; mt < 8; mt++) {
      #pragma unroll
      for (int r = 0; r < 4; r++) {
        int ch = mt * 16 + q * 4 + r;
        out[((size_t)b * C2 + ch) * HWSZ + ho * WW + wo] = acc[mt][r] + bias[ch];
      }
    }
  }
}

// ---------------------------------------------------------------------------
extern "C" void kernel_launch(void* const* d_in, const int* in_sizes, int n_in,
                              void* d_out, int out_size, void* d_ws, size_t ws_size,
                              hipStream_t stream) {
  const float* x    = (const float*)d_in[0];   // (16,128,80,80)
  const float* ow   = (const float*)d_in[1];   // (18,128,3,3)
  const float* ob   = (const float*)d_in[2];   // (18,)
  const float* wgt  = (const float*)d_in[3];   // (128,128,3,3)
  const float* bias = (const float*)d_in[4];   // (128,)
  float* out = (float*)d_out;                  // (16,128,80,80)

  // workspace layout (xt first for 16B alignment)
  ushort* xt   = (ushort*)d_ws;                          // 26.2 MB
  ushort* wbf  = (ushort*)((char*)d_ws + 26214400);      // 288 KB
  ushort* wobf = (ushort*)((char*)d_ws + 26214400 + 294912);           // 72 KB
  ushort* zpad = (ushort*)((char*)d_ws + 26214400 + 294912 + 73728);   // 256 B

  xpose_prep_kernel<<<dim3(3920), dim3(256), 0, stream>>>(x, xt, wgt, ow, wbf, wobf, zpad);
  dconv_fused_kernel<<<dim3(1600), dim3(256), 0, stream>>>(xt, wobf, zpad, ob, wbf, bias, out);
}